// Round 1
// baseline (972.908 us; speedup 1.0000x reference)
//
#include <hip/hip_runtime.h>
#include <math.h>

#define K_TPLT 16
#define M_NODES 10
#define DFEAT 128
#define NMAX 7            // supports up to 448 nodes per graph (actual: 400)
#define N_ITER 50
#define NEG_BIG -1e30f

__global__ void zero_counts_k(int* counts, int G) {
    int g = blockIdx.x * blockDim.x + threadIdx.x;
    if (g < G) counts[g] = 0;
}

__global__ void count_nodes_k(const int* __restrict__ batch, int* counts, int N) {
    int i = blockIdx.x * blockDim.x + threadIdx.x;
    if (i < N) atomicAdd(&counts[batch[i]], 1);
}

__global__ void scan_counts_k(const int* __restrict__ counts, int* starts, int G) {
    __shared__ int sc[1024];
    int t = threadIdx.x;
    for (int g = t; g < G; g += blockDim.x) sc[g] = counts[g];
    __syncthreads();
    for (int g = t; g < G; g += blockDim.x) {
        int s = 0;
        for (int j = 0; j < g; ++j) s += sc[j];
        starts[g] = s;
    }
}

// One wave (64 threads) per (graph, template) problem.
__global__ __launch_bounds__(64) void sinkhorn_tw_k(
    const float* __restrict__ x, const float* __restrict__ tplt,
    const float* __restrict__ q0, const int* __restrict__ starts,
    const int* __restrict__ counts, float* __restrict__ out, int G)
{
    const int bid  = blockIdx.x;
    const int g    = bid % G;      // same-g blocks land on same XCD (G % 8 == 0)
    const int k    = bid / G;
    const int lane = threadIdx.x;

    const int start = starts[g];
    const int count = counts[g];
    const float log_a     = -__logf((float)count);
    const float inv_count = 1.0f / (float)count;

    // log_b[m] = log_softmax(q0[k, :])
    const float* qk = q0 + k * M_NODES;
    float lb[M_NODES];
    {
        float qmax = NEG_BIG;
#pragma unroll
        for (int m = 0; m < M_NODES; ++m) { lb[m] = qk[m]; qmax = fmaxf(qmax, lb[m]); }
        float qs = 0.f;
#pragma unroll
        for (int m = 0; m < M_NODES; ++m) qs += __expf(lb[m] - qmax);
        const float corr = qmax + __logf(qs);
#pragma unroll
        for (int m = 0; m < M_NODES; ++m) lb[m] -= corr;
    }

    // negC[i][m] = -||x_n - T_km||^2 = 2<x_n,T_km> - |x_n|^2 - |T_km|^2
    bool act[NMAX];
#pragma unroll
    for (int i = 0; i < NMAX; ++i) act[i] = (lane + i * 64) < count;

    float negC[NMAX][M_NODES];
    {
        const float* Tk = tplt + (size_t)k * M_NODES * DFEAT;
        float x2[NMAX];
        float t2[M_NODES];
#pragma unroll
        for (int i = 0; i < NMAX; ++i) {
            x2[i] = 0.f;
#pragma unroll
            for (int m = 0; m < M_NODES; ++m) negC[i][m] = 0.f;
        }
#pragma unroll
        for (int m = 0; m < M_NODES; ++m) t2[m] = 0.f;

        for (int j = 0; j < DFEAT; j += 4) {
            float4 xv[NMAX];
#pragma unroll
            for (int i = 0; i < NMAX; ++i) {
                if (act[i]) {
                    xv[i] = *(const float4*)(x + (size_t)(start + lane + i * 64) * DFEAT + j);
                } else {
                    xv[i].x = xv[i].y = xv[i].z = xv[i].w = 0.f;
                }
                x2[i] += xv[i].x * xv[i].x + xv[i].y * xv[i].y
                       + xv[i].z * xv[i].z + xv[i].w * xv[i].w;
            }
#pragma unroll
            for (int m = 0; m < M_NODES; ++m) {
                const float4 tv = *(const float4*)(Tk + m * DFEAT + j);
                t2[m] += tv.x * tv.x + tv.y * tv.y + tv.z * tv.z + tv.w * tv.w;
#pragma unroll
                for (int i = 0; i < NMAX; ++i) {
                    negC[i][m] += xv[i].x * tv.x + xv[i].y * tv.y
                                + xv[i].z * tv.z + xv[i].w * tv.w;
                }
            }
        }
#pragma unroll
        for (int i = 0; i < NMAX; ++i)
#pragma unroll
            for (int m = 0; m < M_NODES; ++m)
                negC[i][m] = 2.f * negC[i][m] - x2[i] - t2[m];
    }

    // Sinkhorn iterations (EPS = 1)
    float gm[M_NODES];
#pragma unroll
    for (int m = 0; m < M_NODES; ++m) gm[m] = 0.f;

    for (int it = 0; it < N_ITER; ++it) {
        float Mx[M_NODES], Sm[M_NODES];
#pragma unroll
        for (int m = 0; m < M_NODES; ++m) { Mx[m] = NEG_BIG; Sm[m] = 0.f; }

#pragma unroll
        for (int i = 0; i < NMAX; ++i) {
            if (act[i]) {
                float s[M_NODES];
                float smax = NEG_BIG;
#pragma unroll
                for (int m = 0; m < M_NODES; ++m) {
                    s[m] = gm[m] + negC[i][m];
                    smax = fmaxf(smax, s[m]);
                }
                float S = 0.f;
#pragma unroll
                for (int m = 0; m < M_NODES; ++m) S += __expf(s[m] - smax);
                const float f = log_a - smax - __logf(S);
                // t_m = f - C = f + negC ; online (max,sum) accumulate per m
#pragma unroll
                for (int m = 0; m < M_NODES; ++m) {
                    const float t  = f + negC[i][m];
                    const float nM = fmaxf(Mx[m], t);
                    Sm[m] = Sm[m] * __expf(Mx[m] - nM) + __expf(t - nM);
                    Mx[m] = nM;
                }
            }
        }
        // wave-level logsumexp reduction per m, then g-update
#pragma unroll
        for (int m = 0; m < M_NODES; ++m) {
            float mx = Mx[m];
            for (int off = 32; off > 0; off >>= 1) mx = fmaxf(mx, __shfl_xor(mx, off));
            float sm = Sm[m] * __expf(Mx[m] - mx);
            for (int off = 32; off > 0; off >>= 1) sm += __shfl_xor(sm, off);
            gm[m] = lb[m] - (mx + __logf(sm));
        }
    }

    // Final f-update fused with transport-cost accumulation:
    // per_node = (a/S) * sum_m e_m * C_m  with  e_m = exp(s_m - smax)
    float accum = 0.f;
#pragma unroll
    for (int i = 0; i < NMAX; ++i) {
        if (act[i]) {
            float s[M_NODES];
            float smax = NEG_BIG;
#pragma unroll
            for (int m = 0; m < M_NODES; ++m) {
                s[m] = gm[m] + negC[i][m];
                smax = fmaxf(smax, s[m]);
            }
            float S = 0.f, tsum = 0.f;
#pragma unroll
            for (int m = 0; m < M_NODES; ++m) {
                const float e = __expf(s[m] - smax);
                S    += e;
                tsum += e * (-negC[i][m]);
            }
            accum += (inv_count / S) * tsum;
        }
    }
    for (int off = 32; off > 0; off >>= 1) accum += __shfl_xor(accum, off);
    if (lane == 0) out[(size_t)g * K_TPLT + k] = accum;
}

extern "C" void kernel_launch(void* const* d_in, const int* in_sizes, int n_in,
                              void* d_out, int out_size, void* d_ws, size_t ws_size,
                              hipStream_t stream) {
    const float* x    = (const float*)d_in[0];
    const float* tplt = (const float*)d_in[1];
    const float* q0   = (const float*)d_in[2];
    const int* batch  = (const int*)d_in[3];
    const int N = in_sizes[3];
    const int G = out_size / K_TPLT;

    int* counts = (int*)d_ws;
    int* starts = counts + G;

    zero_counts_k<<<(G + 255) / 256, 256, 0, stream>>>(counts, G);
    count_nodes_k<<<(N + 255) / 256, 256, 0, stream>>>(batch, counts, N);
    scan_counts_k<<<1, 256, 0, stream>>>(counts, starts, G);
    sinkhorn_tw_k<<<G * K_TPLT, 64, 0, stream>>>(x, tplt, q0, starts, counts,
                                                 (float*)d_out, G);
}

// Round 8
// 531.360 us; speedup vs baseline: 1.8310x; 1.8310x over previous
//
#include <hip/hip_runtime.h>

#define K_TPLT 16
#define M_NODES 10
#define DFEAT 128
#define NMAX 7            // supports up to 448 nodes per graph (actual: 400)
#define N_ITER 50
#define NEG_BIG -1e30f
#define LOG2E 1.44269504088896340736f
#define LN2   0.69314718055994530942f

#define EXP2F(x) __builtin_amdgcn_exp2f(x)
#define LOG2F(x) __builtin_amdgcn_logf(x)   // v_log_f32 = log base 2

__global__ void zero_counts_k(int* counts, int G) {
    int g = blockIdx.x * blockDim.x + threadIdx.x;
    if (g < G) counts[g] = 0;
}

__global__ void count_nodes_k(const int* __restrict__ batch, int* counts, int N) {
    int i = blockIdx.x * blockDim.x + threadIdx.x;
    if (i < N) atomicAdd(&counts[batch[i]], 1);
}

__global__ void scan_counts_k(const int* __restrict__ counts, int* starts, int G) {
    __shared__ int sc[1024];
    int t = threadIdx.x;
    for (int g = t; g < G; g += blockDim.x) sc[g] = counts[g];
    __syncthreads();
    for (int g = t; g < G; g += blockDim.x) {
        int s = 0;
        for (int j = 0; j < g; ++j) s += sc[j];
        starts[g] = s;
    }
}

// One wave per (graph, template) problem. C kept in LOG domain (L = negC2 -
// nsh_i, row max == 0); every iteration uses a FRESH per-node row shift
// (mirrors the reference's per-iteration logsumexp re-centering).
// Exact update: g_new = lbla + g2_m - log2(s_m), s_m = sum_i e_im / D_i,
// e = 2^(g2+L-zmax), D = sum_m e in [1,10]. The "+ g2[m]" divides the
// numerator's 2^g2 factor back out (its omission was R6's O(10) error).
// Iteration 1 (g=0, extreme column spread) is computed exactly via the
// per-column shift csh.
__global__ __launch_bounds__(64) void sinkhorn_tw_k(
    const float* __restrict__ x, const float* __restrict__ tplt,
    const float* __restrict__ q0, const int* __restrict__ starts,
    const int* __restrict__ counts, float* __restrict__ out, int G)
{
    const int bid  = blockIdx.x;
    const int g    = bid % G;      // same-g blocks land on same XCD (G % 8 == 0)
    const int k    = bid / G;
    const int lane = threadIdx.x;

    const int start = starts[g];
    const int count = counts[g];
    const float a   = 1.0f / (float)count;
    const float la2 = -LOG2F((float)count);            // log2(a)

    // lbla[m] = log2_softmax(q0[k,:]) - la2
    const float* qk = q0 + k * M_NODES;
    float lbla[M_NODES];
    {
        float qv[M_NODES];
        float qmax = NEG_BIG;
#pragma unroll
        for (int m = 0; m < M_NODES; ++m) { qv[m] = qk[m]; qmax = fmaxf(qmax, qv[m]); }
        float qs = 0.f;
#pragma unroll
        for (int m = 0; m < M_NODES; ++m) {
            qv[m] = (qv[m] - qmax) * LOG2E;
            qs += EXP2F(qv[m]);
        }
        const float corr = LOG2F(qs);
#pragma unroll
        for (int m = 0; m < M_NODES; ++m) lbla[m] = qv[m] - corr - la2;
    }

    bool act[NMAX];
#pragma unroll
    for (int i = 0; i < NMAX; ++i) act[i] = (lane + i * 64) < count;

    // L[i][m] = (negC * log2e) - nsh_i  (log2 domain, <= 0, row max == 0)
    float L[NMAX][M_NODES];
    float nsh[NMAX];
    float csh[M_NODES];
    {
        const float* Tk = tplt + (size_t)k * M_NODES * DFEAT;
        float x2[NMAX];
        float t2[M_NODES];
#pragma unroll
        for (int i = 0; i < NMAX; ++i) {
            x2[i] = 0.f;
#pragma unroll
            for (int m = 0; m < M_NODES; ++m) L[i][m] = 0.f;
        }
#pragma unroll
        for (int m = 0; m < M_NODES; ++m) t2[m] = 0.f;

        for (int j = 0; j < DFEAT; j += 4) {
            float4 xv[NMAX];
#pragma unroll
            for (int i = 0; i < NMAX; ++i) {
                if (act[i]) {
                    xv[i] = *(const float4*)(x + (size_t)(start + lane + i * 64) * DFEAT + j);
                } else {
                    xv[i].x = xv[i].y = xv[i].z = xv[i].w = 0.f;
                }
                x2[i] += xv[i].x * xv[i].x + xv[i].y * xv[i].y
                       + xv[i].z * xv[i].z + xv[i].w * xv[i].w;
            }
#pragma unroll
            for (int m = 0; m < M_NODES; ++m) {
                const float4 tv = *(const float4*)(Tk + m * DFEAT + j);
                t2[m] += tv.x * tv.x + tv.y * tv.y + tv.z * tv.z + tv.w * tv.w;
#pragma unroll
                for (int i = 0; i < NMAX; ++i) {
                    L[i][m] += xv[i].x * tv.x + xv[i].y * tv.y
                             + xv[i].z * tv.z + xv[i].w * tv.w;
                }
            }
        }
#pragma unroll
        for (int i = 0; i < NMAX; ++i) {
            float mx = NEG_BIG;
#pragma unroll
            for (int m = 0; m < M_NODES; ++m) {
                L[i][m] = (2.f * L[i][m] - x2[i] - t2[m]) * LOG2E;   // negC2
                mx = fmaxf(mx, L[i][m]);
            }
            nsh[i] = mx;
#pragma unroll
            for (int m = 0; m < M_NODES; ++m) L[i][m] -= mx;         // <= 0
        }
        // csh_m = column max of L over active entries (<= 0)
#pragma unroll
        for (int m = 0; m < M_NODES; ++m) {
            float c = NEG_BIG;
#pragma unroll
            for (int i = 0; i < NMAX; ++i) c = act[i] ? fmaxf(c, L[i][m]) : c;
            for (int off = 32; off > 0; off >>= 1) c = fmaxf(c, __shfl_xor(c, off));
            csh[m] = c;
        }
    }

    float g2[M_NODES];

    // ---- iteration 1: g = 0, exact with per-column shift csh ----
    {
        float w0[M_NODES], acc[M_NODES];
#pragma unroll
        for (int m = 0; m < M_NODES; ++m) { w0[m] = EXP2F(csh[m]); acc[m] = 0.f; }
#pragma unroll
        for (int i = 0; i < NMAX; ++i) {
            if (act[i]) {
                float E[M_NODES];
                float D = 0.f;
#pragma unroll
                for (int m = 0; m < M_NODES; ++m) {
                    E[m] = EXP2F(L[i][m] - csh[m]);     // <= 1, col max == 1
                    D = fmaf(E[m], w0[m], D);           // = sum 2^L, >= 1
                }
                const float r = __builtin_amdgcn_rcpf(D);
#pragma unroll
                for (int m = 0; m < M_NODES; ++m) acc[m] = fmaf(E[m], r, acc[m]);
            }
        }
#pragma unroll
        for (int m = 0; m < M_NODES; ++m) {
            float s = acc[m];
            for (int off = 32; off > 0; off >>= 1) s += __shfl_xor(s, off);
            g2[m] = lbla[m] - csh[m] - LOG2F(fmaxf(s, 1e-35f));
        }
    }

    // ---- iterations 2..N_ITER: fresh per-node row shift each time ----
    for (int it = 1; it < N_ITER; ++it) {
        float acc[M_NODES];
#pragma unroll
        for (int m = 0; m < M_NODES; ++m) acc[m] = 0.f;

#pragma unroll
        for (int i = 0; i < NMAX; ++i) {
            if (act[i]) {
                float e[M_NODES];
                float zmax = NEG_BIG;
#pragma unroll
                for (int m = 0; m < M_NODES; ++m) {
                    e[m] = g2[m] + L[i][m];
                    zmax = fmaxf(zmax, e[m]);
                }
                float D = 0.f;
#pragma unroll
                for (int m = 0; m < M_NODES; ++m) { e[m] = EXP2F(e[m] - zmax); D += e[m]; }
                const float r = __builtin_amdgcn_rcpf(D);   // D in [1,10]
#pragma unroll
                for (int m = 0; m < M_NODES; ++m) acc[m] = fmaf(e[m], r, acc[m]);
            }
        }
#pragma unroll
        for (int m = 0; m < M_NODES; ++m) {
            float s = acc[m];
            for (int off = 32; off > 0; off >>= 1) s += __shfl_xor(s, off);
            g2[m] = lbla[m] + g2[m] - LOG2F(fmaxf(s, 1e-35f));   // + g2[m]: exact update
        }
    }

    // ---- epilogue: final f fused with transport cost ----
    // P[n,m] = a * e_m * r_n ; C = -ln2*(L + nsh)
    // per_node = -a*ln2*( nsh_i + r * sum_m e_m L_m )
    float accum = 0.f;
#pragma unroll
    for (int i = 0; i < NMAX; ++i) {
        if (act[i]) {
            float e[M_NODES];
            float zmax = NEG_BIG;
#pragma unroll
            for (int m = 0; m < M_NODES; ++m) {
                e[m] = g2[m] + L[i][m];
                zmax = fmaxf(zmax, e[m]);
            }
            float D = 0.f;
#pragma unroll
            for (int m = 0; m < M_NODES; ++m) { e[m] = EXP2F(e[m] - zmax); D += e[m]; }
            const float r = __builtin_amdgcn_rcpf(D);
            float q = 0.f;
#pragma unroll
            for (int m = 0; m < M_NODES; ++m) q = fmaf(e[m], L[i][m], q);
            accum += nsh[i] + q * r;
        }
    }
    for (int off = 32; off > 0; off >>= 1) accum += __shfl_xor(accum, off);
    if (lane == 0) out[(size_t)g * K_TPLT + k] = -a * LN2 * accum;
}

extern "C" void kernel_launch(void* const* d_in, const int* in_sizes, int n_in,
                              void* d_out, int out_size, void* d_ws, size_t ws_size,
                              hipStream_t stream) {
    const float* x    = (const float*)d_in[0];
    const float* tplt = (const float*)d_in[1];
    const float* q0   = (const float*)d_in[2];
    const int* batch  = (const int*)d_in[3];
    const int N = in_sizes[3];
    const int G = out_size / K_TPLT;

    int* counts = (int*)d_ws;
    int* starts = counts + G;

    zero_counts_k<<<(G + 255) / 256, 256, 0, stream>>>(counts, G);
    count_nodes_k<<<(N + 255) / 256, 256, 0, stream>>>(batch, counts, N);
    scan_counts_k<<<1, 256, 0, stream>>>(counts, starts, G);
    sinkhorn_tw_k<<<G * K_TPLT, 64, 0, stream>>>(x, tplt, q0, starts, counts,
                                                 (float*)d_out, G);
}